// Round 1
// baseline (1157.964 us; speedup 1.0000x reference)
//
#include <hip/hip_runtime.h>
#include <hip/hip_bf16.h>
#include <math.h>

#define N_B 4
#define H_H 12
#define T_T 1024
#define D_H 64
#define F_F 266
#define N_H 48          // N_B*H_H
#define TM_ 128
#define KSEL 98304u     // kk*T*H = 8*1024*12
#define PER_BATCH 1572864  // H*T*TM

static __device__ __forceinline__ float waveSum(float v){
  for(int o=32;o;o>>=1) v += __shfl_xor(v,o,64);
  return v;
}
static __device__ __forceinline__ float waveMax(float v){
  for(int o=32;o;o>>=1) v = fmaxf(v,__shfl_xor(v,o,64));
  return v;
}

#define DN_C 0.35355339059327373f   // 64^-0.25 = 2^-1.5
#define DIAG_C 0.0625f              // 0.5 * 64^-0.5
#define RATIO_C 0.06131393394849658f // 266^-0.5
#define EPS_C 1e-4f

// ---------------- Kernel A: per-(head, t-chunk) max of dd for keys ----------
__global__ __launch_bounds__(256) void kmax_kern(
    const float* __restrict__ kfa, const float* __restrict__ pm,
    float* __restrict__ keymax){
  int head = blockIdx.x, tc = blockIdx.y;
  __shared__ float xs[64][65];
  __shared__ float red[4];
  const float* xp = kfa + ((size_t)head*T_T + (size_t)tc*64)*D_H;
  for(int i=threadIdx.x;i<64*64;i+=256) xs[i>>6][i&63] = xp[i];
  __syncthreads();
  int lane = threadIdx.x&63, w = threadIdx.x>>6;
  float mx = -3.4e38f;
  for(int f=w; f<F_F; f+=4){
    const float* pr = pm + f*D_H;
    float s0=0,s1=0,s2=0,s3=0;
    for(int d=0; d<64; d+=4){
      s0 += xs[lane][d]*pr[d];   s1 += xs[lane][d+1]*pr[d+1];
      s2 += xs[lane][d+2]*pr[d+2]; s3 += xs[lane][d+3]*pr[d+3];
    }
    mx = fmaxf(mx, DN_C*((s0+s1)+(s2+s3)));
  }
  mx = waveMax(mx);
  if(lane==0) red[w]=mx;
  __syncthreads();
  if(threadIdx.x==0)
    keymax[head*16+tc] = fmaxf(fmaxf(red[0],red[1]),fmaxf(red[2],red[3]));
}

// ---------------- Kernel B: key features -> ctx[head][f][d], ksum[head][f] --
__global__ __launch_bounds__(256) void keyfeat_kern(
    const float* __restrict__ kfa, const float* __restrict__ pm,
    const float* __restrict__ mask, const float* __restrict__ keymax,
    float* __restrict__ ctx, float* __restrict__ ksum){
  int head = blockIdx.x, fc = blockIdx.y;
  int f0 = fc*40, nf = min(40, F_F - f0);
  int n = head / H_H;
  __shared__ float pms[40*64];
  __shared__ float xs[64][65];
  __shared__ float ctxs[40][64];
  __shared__ float ksums[40];
  float m = keymax[head*16];
  for(int i=1;i<16;i++) m = fmaxf(m, keymax[head*16+i]);
  for(int i=threadIdx.x;i<40*64;i+=256) ((float*)ctxs)[i]=0.f;
  for(int i=threadIdx.x;i<40;i+=256) ksums[i]=0.f;
  for(int i=threadIdx.x;i<nf*64;i+=256) pms[i] = pm[f0*64+i];
  int lane = threadIdx.x&63, w = threadIdx.x>>6;
  const float* mrow = mask + n*T_T;
  for(int tc=0;tc<16;tc++){
    __syncthreads();
    const float* xp = kfa + ((size_t)head*T_T + (size_t)tc*64)*D_H;
    for(int i=threadIdx.x;i<64*64;i+=256) xs[i>>6][i&63]=xp[i];
    __syncthreads();
    float diag=0.f;
    for(int d=0;d<64;d++){ float xv=xs[lane][d]; diag += xv*xv; }
    diag *= DIAG_C;
    int tg = tc*64 + lane;
    float vfac = (mrow[tg] > -1.0f) ? 1.f : 0.f;
    for(int fl=w; fl<nf; fl+=4){
      const float* pr = pms + fl*64;
      float s0=0,s1=0,s2=0,s3=0;
      for(int d=0;d<64;d+=4){
        s0+=xs[lane][d]*pr[d];   s1+=xs[lane][d+1]*pr[d+1];
        s2+=xs[lane][d+2]*pr[d+2]; s3+=xs[lane][d+3]*pr[d+3];
      }
      float dd = DN_C*((s0+s1)+(s2+s3));
      float kp = RATIO_C*(expf(dd - diag - m) + EPS_C);
      float tot = waveSum(kp);
      if(lane==0) ksums[fl] += tot;
      float kv = kp*vfac;
      kv += __shfl_down(kv,4,64); kv += __shfl_down(kv,2,64); kv += __shfl_down(kv,1,64);
      if((lane&15)==0) ctxs[fl][tg>>4] += kv;   // only t%16==0 lanes (t//8 even)
    }
  }
  __syncthreads();
  float* co = ctx + ((size_t)head*F_F + f0)*64;
  for(int i=threadIdx.x;i<nf*64;i+=256) co[i] = ((float*)ctxs)[i];
  float* ko = ksum + head*F_F + f0;
  for(int i=threadIdx.x;i<nf;i+=256) ko[i] = ksums[i];
}

// ---------------- Kernel C: query features + pcl --------------------------
__global__ __launch_bounds__(128) void qfeat_kern(
    const float* __restrict__ qfa, const float* __restrict__ pm,
    const float* __restrict__ ctx, const float* __restrict__ ksum,
    float* __restrict__ pcl){
  int head = blockIdx.x, tc = blockIdx.y;   // grid (48,8), 128 threads
  int t = tc*128 + threadIdx.x;
  __shared__ float pms[40*64];
  __shared__ float ctxs[40*64];
  __shared__ float ksums[40];
  const float* xp = qfa + ((size_t)head*T_T + t)*D_H;
  float4 xr[16];
  #pragma unroll
  for(int kk=0;kk<16;kk++) xr[kk] = ((const float4*)xp)[kk];
  float diag = 0.f;
  #pragma unroll
  for(int kk=0;kk<16;kk++)
    diag += xr[kk].x*xr[kk].x + xr[kk].y*xr[kk].y + xr[kk].z*xr[kk].z + xr[kk].w*xr[kk].w;
  diag *= DIAG_C;
  // sweep 1: row max of dd
  float m = -3.4e38f;
  for(int fcc=0;fcc<7;fcc++){
    int f0 = fcc*40, nf = min(40, F_F-f0);
    __syncthreads();
    for(int i=threadIdx.x;i<nf*64;i+=128) pms[i] = pm[f0*64+i];
    __syncthreads();
    for(int fl=0; fl<nf; fl++){
      const float4* pr = (const float4*)(pms + fl*64);
      float s0=0,s1=0,s2=0,s3=0;
      #pragma unroll
      for(int kk=0;kk<16;kk++){ float4 w4 = pr[kk];
        s0+=xr[kk].x*w4.x; s1+=xr[kk].y*w4.y; s2+=xr[kk].z*w4.z; s3+=xr[kk].w*w4.w; }
      m = fmaxf(m, DN_C*((s0+s1)+(s2+s3)));
    }
  }
  // sweep 2: qp, denominator, pcl accumulation
  float4 acc[16];
  #pragma unroll
  for(int kk=0;kk<16;kk++) acc[kk] = make_float4(0.f,0.f,0.f,0.f);
  float den = 0.f;
  for(int fcc=0;fcc<7;fcc++){
    int f0=fcc*40, nf=min(40,F_F-f0);
    __syncthreads();
    for(int i=threadIdx.x;i<nf*64;i+=128){
      pms[i]=pm[f0*64+i];
      ctxs[i]=ctx[((size_t)head*F_F+f0)*64 + i];
    }
    for(int i=threadIdx.x;i<nf;i+=128) ksums[i]=ksum[head*F_F+f0+i];
    __syncthreads();
    for(int fl=0; fl<nf; fl++){
      const float4* pr=(const float4*)(pms+fl*64);
      float s0=0,s1=0,s2=0,s3=0;
      #pragma unroll
      for(int kk=0;kk<16;kk++){ float4 w4=pr[kk];
        s0+=xr[kk].x*w4.x; s1+=xr[kk].y*w4.y; s2+=xr[kk].z*w4.z; s3+=xr[kk].w*w4.w; }
      float dd = DN_C*((s0+s1)+(s2+s3));
      float qp = RATIO_C*(expf(dd - diag - m) + EPS_C);
      den += qp*ksums[fl];
      const float4* cr=(const float4*)(ctxs+fl*64);
      #pragma unroll
      for(int kk=0;kk<16;kk++){ float4 c4=cr[kk];
        acc[kk].x+=qp*c4.x; acc[kk].y+=qp*c4.y; acc[kk].z+=qp*c4.z; acc[kk].w+=qp*c4.w; }
    }
  }
  float dinv = 1.0f/den;
  float* po = pcl + ((size_t)head*T_T + t)*D_H;
  #pragma unroll
  for(int kk=0;kk<16;kk++){
    po[4*kk+0]=acc[kk].x*dinv; po[4*kk+1]=acc[kk].y*dinv;
    po[4*kk+2]=acc[kk].z*dinv; po[4*kk+3]=acc[kk].w*dinv;
  }
}

// ---------------- Kernel D: MLP + LN + GELU + score + softmax -------------
__global__ __launch_bounds__(256) void mlp_kern(
    const float* __restrict__ pcl, const float* __restrict__ v,
    const float* __restrict__ mask,
    const float* __restrict__ encw, const float* __restrict__ encb,
    const float* __restrict__ lng, const float* __restrict__ lnb,
    const float* __restrict__ decw, const float* __restrict__ decb,
    float* __restrict__ probsout, float* __restrict__ scoreout){
  int head = blockIdx.x, tblk = blockIdx.y;   // grid (48,32)
  int t0 = tblk*32;
  int n = head / H_H;
  __shared__ float pvs[32][129];
  __shared__ float wts[32][128];
  __shared__ float h1s[32][129];
  const float* pclrow = pcl + ((size_t)head*T_T + t0)*D_H;
  const float* vrow   = v   + ((size_t)head*T_T + t0)*D_H;
  for(int i=threadIdx.x;i<32*64;i+=256){
    int r=i>>6, c=i&63;
    pvs[r][c]   = pclrow[i];
    pvs[r][64+c]= vrow[i];
  }
  int tl = threadIdx.x>>3, g = threadIdx.x&7;  // row, col-group
  float acc[16];
  #pragma unroll
  for(int jj=0;jj<16;jj++) acc[jj] = encb[g+8*jj];
  for(int kc=0;kc<4;kc++){
    __syncthreads();
    for(int i=threadIdx.x;i<32*128;i+=256) ((float*)wts)[i] = encw[kc*32*128 + i];
    __syncthreads();
    for(int k=0;k<32;k++){
      float x = pvs[tl][kc*32+k];
      #pragma unroll
      for(int jj=0;jj<16;jj++) acc[jj] += x*wts[k][g+8*jj];
    }
  }
  // LayerNorm (two-pass, matches reference)
  float s1=0;
  #pragma unroll
  for(int jj=0;jj<16;jj++) s1+=acc[jj];
  for(int o=1;o<8;o<<=1) s1 += __shfl_xor(s1,o,64);
  float mu = s1*(1.0f/128.0f);
  float s2=0;
  #pragma unroll
  for(int jj=0;jj<16;jj++){ float d=acc[jj]-mu; s2+=d*d; }
  for(int o=1;o<8;o<<=1) s2 += __shfl_xor(s2,o,64);
  float var = s2*(1.0f/128.0f);
  float denom = sqrtf(var+1e-5f);
  #pragma unroll
  for(int jj=0;jj<16;jj++){
    int j=g+8*jj;
    float hv = (acc[jj]-mu)/denom*lng[j]+lnb[j];
    hv = hv*0.5f*(1.0f+erff(hv*0.70710678118654752f));  // exact gelu
    h1s[tl][j]=hv;
  }
  float acc2[16];
  #pragma unroll
  for(int jj=0;jj<16;jj++) acc2[jj]=decb[g+8*jj];
  for(int kc=0;kc<4;kc++){
    __syncthreads();
    for(int i=threadIdx.x;i<32*128;i+=256) ((float*)wts)[i]=decw[kc*32*128+i];
    __syncthreads();
    for(int k=0;k<32;k++){
      float x=h1s[tl][kc*32+k];
      #pragma unroll
      for(int jj=0;jj<16;jj++) acc2[jj]+=x*wts[k][g+8*jj];
    }
  }
  // masked softmax (rmask = mask[..., j*8])
  const float* mrow = mask + n*T_T;
  float sm[16]; float mx=-3.4e38f;
  #pragma unroll
  for(int jj=0;jj<16;jj++){
    int j=g+8*jj;
    float rm = mrow[j*8];
    float val = (rm < -1.0f) ? -10000.0f : acc2[jj];
    sm[jj]=val; mx=fmaxf(mx,val);
  }
  for(int o=1;o<8;o<<=1) mx=fmaxf(mx,__shfl_xor(mx,o,64));
  float Z=0;
  #pragma unroll
  for(int jj=0;jj<16;jj++){ sm[jj]=expf(sm[jj]-mx); Z+=sm[jj]; }
  for(int o=1;o<8;o<<=1) Z+=__shfl_xor(Z,o,64);
  float zi=1.0f/Z;
  size_t rbase=((size_t)head*T_T + t0+tl)*TM_;
  #pragma unroll
  for(int jj=0;jj<16;jj++){
    int j=g+8*jj;
    probsout[rbase+j]=sm[jj]*zi;
    scoreout[rbase+j]=acc2[jj];
  }
}

// ---------------- Kernel E: per-row KL + MSE ------------------------------
__global__ __launch_bounds__(256) void loss_kern(
    const float* __restrict__ truth, const float* __restrict__ mask,
    const float* __restrict__ score, float* __restrict__ klrow,
    float* __restrict__ mserow){
  int row = blockIdx.x;               // head*1024 + t
  int n = row / (H_H*T_T);
  __shared__ float a[1024];
  __shared__ float mk[1024];
  __shared__ float sc[128];
  __shared__ float red4[4];
  const float* ar = truth + (size_t)row*T_T;
  const float* mr = mask + n*T_T;
  const float* sr = score + (size_t)row*TM_;
  if(threadIdx.x < 256){
    ((float4*)a)[threadIdx.x]  = ((const float4*)ar)[threadIdx.x];
    ((float4*)mk)[threadIdx.x] = ((const float4*)mr)[threadIdx.x];
  }
  for(int i=threadIdx.x;i<128;i+=256) sc[i]=sr[i];   // unaligned base -> scalar
  __syncthreads();
  float ma=-3.4e38f, ms=-3.4e38f;
  for(int j=threadIdx.x;j<1024;j+=256){
    ma=fmaxf(ma,a[j]+mk[j]);
    ms=fmaxf(ms,sc[j>>3]+mk[j]);
  }
  ma = waveMax(ma);
  if((threadIdx.x&63)==0) red4[threadIdx.x>>6]=ma;
  __syncthreads();
  ma = fmaxf(fmaxf(red4[0],red4[1]),fmaxf(red4[2],red4[3]));
  __syncthreads();
  ms = waveMax(ms);
  if((threadIdx.x&63)==0) red4[threadIdx.x>>6]=ms;
  __syncthreads();
  ms = fmaxf(fmaxf(red4[0],red4[1]),fmaxf(red4[2],red4[3]));
  __syncthreads();
  float Za=0, Zs=0;
  for(int j=threadIdx.x;j<1024;j+=256){
    Za += expf(a[j]+mk[j]-ma);
    Zs += expf(sc[j>>3]+mk[j]-ms);
  }
  Za = waveSum(Za);
  if((threadIdx.x&63)==0) red4[threadIdx.x>>6]=Za;
  __syncthreads();
  Za = (red4[0]+red4[1])+(red4[2]+red4[3]);
  __syncthreads();
  Zs = waveSum(Zs);
  if((threadIdx.x&63)==0) red4[threadIdx.x>>6]=Zs;
  __syncthreads();
  Zs = (red4[0]+red4[1])+(red4[2]+red4[3]);
  __syncthreads();
  float lZs = logf(Zs);
  float kl=0, mse=0;
  for(int j=threadIdx.x;j<1024;j+=256){
    float mkj = mk[j];
    float scj = sc[j>>3];
    float aj = a[j];
    if(mkj > -1.0f){
      float pt = expf(aj+mkj-ma)/Za;
      float logpt = logf(fmaxf(pt,1e-12f));
      float logp = (scj+mkj-ms) - lZs;
      kl += pt*(logpt-logp);
    }
    float sv = (mkj < -1.0f)?0.f:scj;
    float av = (mkj < -1.0f)?0.f:aj;
    float d = sv-av; mse += d*d;
  }
  kl = waveSum(kl);
  if((threadIdx.x&63)==0) red4[threadIdx.x>>6]=kl;
  __syncthreads();
  kl = (red4[0]+red4[1])+(red4[2]+red4[3]);
  __syncthreads();
  mse = waveSum(mse);
  if((threadIdx.x&63)==0) red4[threadIdx.x>>6]=mse;
  __syncthreads();
  if(threadIdx.x==0){
    mse = (red4[0]+red4[1])+(red4[2]+red4[3]);
    klrow[row]=kl; mserow[row]=mse;
  }
}

// ---------------- Kernel F: final loss ------------------------------------
__global__ __launch_bounds__(256) void finloss_kern(
    const float* __restrict__ klrow, const float* __restrict__ mserow,
    const float* __restrict__ mask, float* __restrict__ out0){
  __shared__ double reds[256];
  double kls=0, mses=0;
  for(int i=threadIdx.x;i<N_H*T_T;i+=256){ kls+=(double)klrow[i]; mses+=(double)mserow[i]; }
  double vcnt=0;
  for(int i=threadIdx.x;i<N_B*T_T;i+=256) if(mask[i] > -1.0f) vcnt+=1.0;
  reds[threadIdx.x]=kls; __syncthreads();
  for(int o=128;o;o>>=1){ if(threadIdx.x<o) reds[threadIdx.x]+=reds[threadIdx.x+o]; __syncthreads(); }
  double klsum = reds[0]; __syncthreads();
  reds[threadIdx.x]=mses; __syncthreads();
  for(int o=128;o;o>>=1){ if(threadIdx.x<o) reds[threadIdx.x]+=reds[threadIdx.x+o]; __syncthreads(); }
  double msesum = reds[0]; __syncthreads();
  reds[threadIdx.x]=vcnt; __syncthreads();
  for(int o=128;o;o>>=1){ if(threadIdx.x<o) reds[threadIdx.x]+=reds[threadIdx.x+o]; __syncthreads(); }
  if(threadIdx.x==0){
    double denom = reds[0] * (double)(H_H*T_T);
    double loss = klsum/denom*0.25 + msesum/((double)N_B*H_H*T_T*T_T);
    out0[0]=(float)loss;
  }
}

// ---------------- Top-k pipeline ------------------------------------------
__global__ void topk_init(unsigned* __restrict__ hist, unsigned* __restrict__ state,
                          unsigned* __restrict__ tiecnt){
  int i = blockIdx.x*256+threadIdx.x;
  if(i < 4*256) hist[i]=0;
  if(i < 4){ state[i*4+0]=0u; state[i*4+1]=KSEL; state[i*4+2]=0u; tiecnt[i]=0u; }
}

__global__ __launch_bounds__(256) void topk_hist(
    const float* __restrict__ probs, const float* __restrict__ mask,
    const unsigned* __restrict__ state, unsigned* __restrict__ hist, int level){
  __shared__ unsigned lh[4*256];
  for(int i=threadIdx.x;i<1024;i+=256) lh[i]=0;
  __syncthreads();
  unsigned pmask = (level==0)?0u:(0xFFFFFFFFu << (32-8*level));
  unsigned pref[4];
  for(int b=0;b<4;b++) pref[b]=state[b*4+0] & pmask;
  int shift = 24-8*level;
  size_t total = (size_t)N_B*PER_BATCH;
  for(size_t idx = (size_t)blockIdx.x*256+threadIdx.x; idx < total; idx += (size_t)gridDim.x*256){
    int b = (int)(idx / PER_BATCH);
    unsigned r = (unsigned)(idx - (size_t)b*PER_BATCH);
    int t = (int)((r>>7)&1023u);
    float val = probs[idx];
    if(!(mask[b*T_T+t] > -1.0f)) val = 0.0f;
    unsigned u = __float_as_uint(val);
    if((u & pmask) == pref[b]) atomicAdd(&lh[b*256+((u>>shift)&255u)],1u);
  }
  __syncthreads();
  for(int i=threadIdx.x;i<1024;i+=256){
    unsigned c = lh[i];
    if(c) atomicAdd(&hist[i], c);
  }
}

__global__ void topk_scan(unsigned* __restrict__ hist, unsigned* __restrict__ state, int level){
  int b = blockIdx.x;
  if(threadIdx.x==0){
    const unsigned* h = hist + b*256;
    unsigned remk = state[b*4+1];
    unsigned cum = 0; int sel=0;
    for(int bin=255; bin>=0; bin--){
      unsigned c = h[bin];
      if(remk <= cum + c){ sel=bin; break; }
      cum += c;
    }
    state[b*4+0] |= ((unsigned)sel) << (24-8*level);
    state[b*4+1] = remk - cum;
    state[b*4+2] += cum;
  }
  __syncthreads();
  for(int i=threadIdx.x;i<256;i+=blockDim.x) hist[b*256+i]=0;
}

__global__ __launch_bounds__(256) void topk_write(
    const float* __restrict__ probs, const float* __restrict__ mask,
    const unsigned* __restrict__ state, float* __restrict__ pam,
    unsigned* __restrict__ ties, unsigned* __restrict__ tiecnt){
  unsigned thr[4];
  for(int b=0;b<4;b++) thr[b]=state[b*4+0];
  size_t total=(size_t)N_B*PER_BATCH;
  for(size_t idx=(size_t)blockIdx.x*256+threadIdx.x; idx<total; idx += (size_t)gridDim.x*256){
    int b = (int)(idx / PER_BATCH);
    unsigned r = (unsigned)(idx - (size_t)b*PER_BATCH);
    int t = (int)((r>>7)&1023u);
    float val = probs[idx];
    if(!(mask[b*T_T+t] > -1.0f)) val=0.0f;
    unsigned u=__float_as_uint(val);
    float o = -10000.0f;
    if(u > thr[b]) o = 0.0f;
    else if(u == thr[b]){
      unsigned pos = atomicAdd(&tiecnt[b],1u);
      if(pos < 65536u) ties[(size_t)b*65536+pos]=r;
    }
    pam[idx]=o;
  }
}

__global__ __launch_bounds__(256) void topk_ties(
    const unsigned* __restrict__ state, const unsigned* __restrict__ ties,
    const unsigned* __restrict__ tiecnt, float* __restrict__ pam){
  int b = blockIdx.x;
  unsigned needed = state[b*4+1];
  unsigned nt = min(tiecnt[b], 65536u);
  __shared__ unsigned redu[256];
  __shared__ unsigned lohi[2];
  if(threadIdx.x==0){ lohi[0]=0u; lohi[1]=PER_BATCH; }
  __syncthreads();
  if(needed == 0 || nt == 0) return;
  // find minimal X with |{tie idx < X}| >= needed (ties broken by lowest index)
  while(true){
    __syncthreads();
    unsigned lo=lohi[0], hi=lohi[1];
    if(hi-lo<=1u) break;
    unsigned mid=(lo+hi)>>1;
    unsigned c=0;
    for(unsigned i=threadIdx.x;i<nt;i+=256) c += (ties[(size_t)b*65536+i] < mid)?1u:0u;
    redu[threadIdx.x]=c; __syncthreads();
    for(int o=128;o;o>>=1){ if(threadIdx.x<o) redu[threadIdx.x]+=redu[threadIdx.x+o]; __syncthreads(); }
    if(threadIdx.x==0){ if(redu[0]>=needed) lohi[1]=mid; else lohi[0]=mid; }
  }
  __syncthreads();
  unsigned X=lohi[1];
  for(unsigned i=threadIdx.x;i<nt;i+=256){
    unsigned r=ties[(size_t)b*65536+i];
    if(r < X) pam[(size_t)b*PER_BATCH + r]=0.0f;
  }
}

// ---------------- launcher ------------------------------------------------
extern "C" void kernel_launch(void* const* d_in, const int* in_sizes, int n_in,
                              void* d_out, int out_size, void* d_ws, size_t ws_size,
                              hipStream_t stream) {
  const float* v     = (const float*)d_in[2];
  const float* qfa   = (const float*)d_in[3];
  const float* kfa   = (const float*)d_in[4];
  const float* mask  = (const float*)d_in[8];
  const float* truth = (const float*)d_in[9];
  const float* pm    = (const float*)d_in[11];
  const float* encw  = (const float*)d_in[12];
  const float* encb  = (const float*)d_in[13];
  const float* lng   = (const float*)d_in[14];
  const float* lnb   = (const float*)d_in[15];
  const float* decw  = (const float*)d_in[16];
  const float* decb  = (const float*)d_in[17];
  float* out = (float*)d_out;
  float* ws  = (float*)d_ws;

  // workspace layout (float units)
  float* keymax = ws;                          // 768
  float* ctx    = ws + 1024;                   // 48*266*64 = 817152
  float* ksum   = ctx + (size_t)N_H*F_F*64;    // 12768
  float* klrow  = ksum + N_H*F_F;              // 49152
  float* mserow = klrow + N_H*T_T;             // 49152
  unsigned* hist   = (unsigned*)(mserow + N_H*T_T); // 1024
  unsigned* state  = hist + 1024;              // 16
  unsigned* tiecnt = state + 16;               // 4
  unsigned* ties   = tiecnt + 12;              // 4*65536

  float* pcl   = out + 1;
  float* probs = pcl + (size_t)N_H*T_T*D_H;
  float* pam   = probs + (size_t)N_H*T_T*TM_;

  kmax_kern<<<dim3(N_H,16),256,0,stream>>>(kfa, pm, keymax);
  keyfeat_kern<<<dim3(N_H,7),256,0,stream>>>(kfa, pm, mask, keymax, ctx, ksum);
  qfeat_kern<<<dim3(N_H,8),128,0,stream>>>(qfa, pm, ctx, ksum, pcl);
  mlp_kern<<<dim3(N_H,32),256,0,stream>>>(pcl, v, mask, encw, encb, lng, lnb,
                                          decw, decb, probs, pam /*score*/);
  loss_kern<<<N_H*T_T,256,0,stream>>>(truth, mask, pam /*score*/, klrow, mserow);
  finloss_kern<<<1,256,0,stream>>>(klrow, mserow, mask, out);
  topk_init<<<4,256,0,stream>>>(hist, state, tiecnt);
  for(int lvl=0;lvl<4;lvl++){
    topk_hist<<<2048,256,0,stream>>>(probs, mask, state, hist, lvl);
    topk_scan<<<4,64,0,stream>>>(hist, state, lvl);
  }
  topk_write<<<2048,256,0,stream>>>(probs, mask, state, pam, ties, tiecnt);
  topk_ties<<<4,256,0,stream>>>(state, ties, tiecnt, pam);
}